// Round 1
// baseline (1632.648 us; speedup 1.0000x reference)
//
#include <hip/hip_runtime.h>
#include <stdint.h>

#define N_TOK 16384
#define DMODEL 1024
#define NEXP 16
#define HDIM 4096
#define NCLS 1000
#define NCLS_PAD 1024
#define CAP 2048

typedef __attribute__((ext_vector_type(8))) short s8v;
typedef __attribute__((ext_vector_type(4))) float f4v;

__device__ inline unsigned short f2bf(float f) {
  unsigned u = __float_as_uint(f);
  u = u + 0x7FFFu + ((u >> 16) & 1u);
  return (unsigned short)(u >> 16);
}

__device__ inline float gelu_f(float v) {
  const float c = 0.7978845608028654f;
  float u = c * (v + 0.044715f * v * v * v);
  return 0.5f * v * (1.0f + tanhf(u));
}

__device__ inline void glds16(const void* g, void* l) {
  __builtin_amdgcn_global_load_lds((const __attribute__((address_space(1))) void*)g,
                                   (__attribute__((address_space(3))) void*)l, 16, 0, 0);
}

// ---------------- transpose fp32 [R][C] -> bf16 [Cpad][R] (zero-pad cols >= C) ----------
__global__ __launch_bounds__(256) void transpose_k(
    const float* __restrict__ in, unsigned short* __restrict__ out,
    int R, int C, long inStride, long outStride) {
  __shared__ float tile[64][65];
  int t = threadIdx.x;
  int c0 = blockIdx.x * 64, r0 = blockIdx.y * 64;
  const float* ip = in + (long)blockIdx.z * inStride;
  unsigned short* op = out + (long)blockIdx.z * outStride;
#pragma unroll
  for (int i = 0; i < 16; i++) {
    int idx = i * 256 + t, r = idx >> 6, c = idx & 63;
    int gc = c0 + c;
    tile[r][c] = (gc < C) ? ip[(long)(r0 + r) * C + gc] : 0.0f;
  }
  __syncthreads();
#pragma unroll
  for (int i = 0; i < 16; i++) {
    int idx = i * 256 + t, r = idx >> 6, c = idx & 63;
    op[(long)(c0 + r) * R + (r0 + c)] = f2bf(tile[c][r]);
  }
}

// ---------------- gating: logits fp32, softmax, argmax(first), x->bf16 ------------------
__global__ __launch_bounds__(256) void gating_k(
    const float* __restrict__ x, const float* __restrict__ Wg,
    unsigned short* __restrict__ xb, int* __restrict__ eidx,
    float* __restrict__ gate, float* __restrict__ psum, unsigned* __restrict__ cnt) {
  __shared__ float psumL[16];
  __shared__ unsigned cntL[16];
  int t = threadIdx.x, lane = t & 63, w = t >> 6;
  if (t < 16) { psumL[t] = 0.f; cntL[t] = 0u; }
  __syncthreads();
  const float4* Wg4 = (const float4*)Wg;
  float pacc[16]; unsigned cacc[16];
#pragma unroll
  for (int e = 0; e < 16; e++) { pacc[e] = 0.f; cacc[e] = 0u; }
  int gw = blockIdx.x * 4 + w;
  int nw = gridDim.x * 4;
  for (int tok = gw; tok < N_TOK; tok += nw) {
    float acc[16];
#pragma unroll
    for (int e = 0; e < 16; e++) acc[e] = 0.f;
    const float* xr = x + (size_t)tok * DMODEL;
#pragma unroll
    for (int s = 0; s < 16; s++) {
      int d = s * 64 + lane;
      float xv = xr[d];
      xb[(size_t)tok * DMODEL + d] = f2bf(xv);
      float4 w0 = Wg4[d * 4 + 0], w1 = Wg4[d * 4 + 1];
      float4 w2 = Wg4[d * 4 + 2], w3 = Wg4[d * 4 + 3];
      acc[0] += xv * w0.x; acc[1] += xv * w0.y; acc[2] += xv * w0.z; acc[3] += xv * w0.w;
      acc[4] += xv * w1.x; acc[5] += xv * w1.y; acc[6] += xv * w1.z; acc[7] += xv * w1.w;
      acc[8] += xv * w2.x; acc[9] += xv * w2.y; acc[10] += xv * w2.z; acc[11] += xv * w2.w;
      acc[12] += xv * w3.x; acc[13] += xv * w3.y; acc[14] += xv * w3.z; acc[15] += xv * w3.w;
    }
#pragma unroll
    for (int e = 0; e < 16; e++) {
      float v = acc[e];
      v += __shfl_xor(v, 32); v += __shfl_xor(v, 16); v += __shfl_xor(v, 8);
      v += __shfl_xor(v, 4);  v += __shfl_xor(v, 2);  v += __shfl_xor(v, 1);
      acc[e] = v;
    }
    float m = acc[0]; int am = 0;
#pragma unroll
    for (int e = 1; e < 16; e++) { if (acc[e] > m) { m = acc[e]; am = e; } }
    float s = 0.f; float p[16];
#pragma unroll
    for (int e = 0; e < 16; e++) { p[e] = expf(acc[e] - m); s += p[e]; }
    float inv = 1.f / s;
#pragma unroll
    for (int e = 0; e < 16; e++) { pacc[e] += p[e] * inv; cacc[e] += (am == e) ? 1u : 0u; }
    if (lane == 0) { eidx[tok] = am; gate[tok] = inv; }
  }
  if (lane == 0) {
#pragma unroll
    for (int e = 0; e < 16; e++) { atomicAdd(&psumL[e], pacc[e]); atomicAdd(&cntL[e], cacc[e]); }
  }
  __syncthreads();
  if (t < 16) { atomicAdd(&psum[t], psumL[t]); atomicAdd(&cnt[t], cntL[t]); }
}

// ---------------- scan: token-order slot assignment (capacity), loss --------------------
__global__ __launch_bounds__(256) void scan_k(
    const int* __restrict__ eidx, int* __restrict__ slot_token,
    const float* __restrict__ psum, const unsigned* __restrict__ cnt,
    float* __restrict__ loss_out) {
  __shared__ int base[16];
  __shared__ int wcnt[4][16];
  __shared__ int wbase[4][16];
  int t = threadIdx.x, lane = t & 63, w = t >> 6;
  if (t < 16) base[t] = 0;
  __syncthreads();
  unsigned long long below = (1ull << lane) - 1ull;
  for (int c0 = 0; c0 < N_TOK; c0 += 256) {
    int tok = c0 + t;
    int e = eidx[tok];
    int rank = 0;
#pragma unroll
    for (int eo = 0; eo < 16; eo++) {
      unsigned long long m = __ballot(e == eo);
      if (lane == eo) wcnt[w][eo] = __popcll(m);
      if (e == eo) rank = __popcll(m & below);
    }
    __syncthreads();
    if (t < 64) {
      int w2 = t >> 4, e2 = t & 15;
      int b = 0;
      for (int ww = 0; ww < w2; ww++) b += wcnt[ww][e2];
      wbase[w2][e2] = b;
    }
    __syncthreads();
    int pos = base[e] + wbase[w][e] + rank;
    if (pos < CAP) slot_token[e * CAP + pos] = tok;
    __syncthreads();
    if (t < 16) {
      int tot = 0;
      for (int ww = 0; ww < 4; ww++) tot += wcnt[ww][t];
      base[t] += tot;
    }
    __syncthreads();
  }
  if (t == 0) {
    float l = 0.f;
    for (int e = 0; e < 16; e++) l += (float)cnt[e] * psum[e];
    loss_out[0] = 16.0f * l / ((float)N_TOK * (float)N_TOK);
  }
}

// ---------------- grouped GEMM, 128x128 tile, BK=32, 4 waves, mfma 16x16x32 bf16 --------
// MODE 0: A = xb gathered via slot_token, B = W1b[e] ([H][D] K-major), epi: gelu(+b1) -> h
// MODE 1: A = h[e], B = W2b[e] ([D][H] K-major), epi: (+b2)*gate scatter -> y[token]
// MODE 2: A = y,    B = Wlb ([1024pad][D]),     epi: (+bl) -> out fp32 (n < 1000)
template<int MODE>
__global__ __launch_bounds__(256, 2) void gemm_k(
    const unsigned short* __restrict__ A, const unsigned short* __restrict__ B,
    const float* __restrict__ bias, unsigned short* __restrict__ obf,
    float* __restrict__ ofp, const int* __restrict__ slot_token,
    const float* __restrict__ gate) {
  constexpr int K = (MODE == 1) ? HDIM : DMODEL;
  __shared__ unsigned short As[128 * 32];
  __shared__ unsigned short Bs[128 * 32];
  int t = threadIdx.x, lane = t & 63, wid = t >> 6;
  int nt = blockIdx.x, mt = blockIdx.y, e = blockIdx.z;
  int r = t >> 2, ch = t & 3;

  const unsigned short *a0, *a1, *b0, *b1;
  if (MODE == 0) {
    int sb = e * CAP + mt * 128;
    int t0 = slot_token[sb + r];      if (t0 < 0) t0 = 0;
    int t1 = slot_token[sb + r + 64]; if (t1 < 0) t1 = 0;
    a0 = A + (size_t)t0 * DMODEL + ch * 8;
    a1 = A + (size_t)t1 * DMODEL + ch * 8;
  } else if (MODE == 1) {
    a0 = A + ((size_t)(e * CAP + mt * 128 + r)) * HDIM + ch * 8;
    a1 = a0 + (size_t)64 * HDIM;
  } else {
    a0 = A + ((size_t)(mt * 128 + r)) * DMODEL + ch * 8;
    a1 = a0 + (size_t)64 * DMODEL;
  }
  if (MODE == 0) {
    b0 = B + ((size_t)(e * HDIM + nt * 128 + r)) * DMODEL + ch * 8;
    b1 = b0 + (size_t)64 * DMODEL;
  } else if (MODE == 1) {
    b0 = B + ((size_t)(e * DMODEL + nt * 128 + r)) * HDIM + ch * 8;
    b1 = b0 + (size_t)64 * HDIM;
  } else {
    b0 = B + ((size_t)(nt * 128 + r)) * DMODEL + ch * 8;
    b1 = b0 + (size_t)64 * DMODEL;
  }

  f4v acc[4][4];
#pragma unroll
  for (int i = 0; i < 4; i++)
#pragma unroll
    for (int j = 0; j < 4; j++)
#pragma unroll
      for (int k = 0; k < 4; k++) acc[i][j][k] = 0.f;

  int fr = lane & 15, fq = lane >> 4;
  int wr = wid >> 1, wc = wid & 1;
  int aof = (wr * 64 + fr) * 32 + fq * 8;
  int bof = (wc * 64 + fr) * 32 + fq * 8;
  unsigned short* AsW = As + wid * 512;   // wave-uniform LDS staging base
  unsigned short* BsW = Bs + wid * 512;

  for (int kt = 0; kt < K / 32; kt++) {
    glds16(a0 + (size_t)kt * 32, AsW);
    glds16(a1 + (size_t)kt * 32, AsW + 2048);
    glds16(b0 + (size_t)kt * 32, BsW);
    glds16(b1 + (size_t)kt * 32, BsW + 2048);
    __syncthreads();
    s8v af[4], bfv[4];
#pragma unroll
    for (int mi = 0; mi < 4; mi++) af[mi] = *(const s8v*)(As + aof + mi * 512);
#pragma unroll
    for (int ni = 0; ni < 4; ni++) bfv[ni] = *(const s8v*)(Bs + bof + ni * 512);
#pragma unroll
    for (int mi = 0; mi < 4; mi++)
#pragma unroll
      for (int ni = 0; ni < 4; ni++)
        asm volatile("v_mfma_f32_16x16x32_bf16 %0, %1, %2, %0"
                     : "+v"(acc[mi][ni]) : "v"(af[mi]), "v"(bfv[ni]));
    __syncthreads();
  }
  asm volatile("s_nop 7\n\ts_nop 7" ::: );  // MFMA->VALU read hazard insurance

  int nbase = nt * 128 + wc * 64;
  int mbase = mt * 128 + wr * 64;
  float bv[4];
#pragma unroll
  for (int ni = 0; ni < 4; ni++) {
    int n = nbase + ni * 16 + fr;
    if (MODE == 0) bv[ni] = bias[e * HDIM + n];
    else if (MODE == 1) bv[ni] = bias[e * DMODEL + n];
    else bv[ni] = (n < NCLS) ? bias[n] : 0.f;
  }
#pragma unroll
  for (int mi = 0; mi < 4; mi++) {
#pragma unroll
    for (int j = 0; j < 4; j++) {
      int mrow = mbase + mi * 16 + fq * 4 + j;
      if (MODE == 0) {
        size_t ro = ((size_t)(e * CAP + mrow)) * HDIM;
#pragma unroll
        for (int ni = 0; ni < 4; ni++) {
          int n = nbase + ni * 16 + fr;
          obf[ro + n] = f2bf(gelu_f(acc[mi][ni][j] + bv[ni]));
        }
      } else if (MODE == 1) {
        int tok = slot_token[e * CAP + mrow];
        if (tok >= 0) {
          float g = gate[tok];
          size_t ro = (size_t)tok * DMODEL;
#pragma unroll
          for (int ni = 0; ni < 4; ni++) {
            int n = nbase + ni * 16 + fr;
            obf[ro + n] = f2bf((acc[mi][ni][j] + bv[ni]) * g);
          }
        }
      } else {
        size_t ro = (size_t)mrow * NCLS;
#pragma unroll
        for (int ni = 0; ni < 4; ni++) {
          int n = nbase + ni * 16 + fr;
          if (n < NCLS) ofp[ro + n] = acc[mi][ni][j] + bv[ni];
        }
      }
    }
  }
}

extern "C" void kernel_launch(void* const* d_in, const int* in_sizes, int n_in,
                              void* d_out, int out_size, void* d_ws, size_t ws_size,
                              hipStream_t stream) {
  const float* x  = (const float*)d_in[0];
  const float* Wg = (const float*)d_in[1];
  const float* W1 = (const float*)d_in[2];
  const float* b1 = (const float*)d_in[3];
  const float* W2 = (const float*)d_in[4];
  const float* b2 = (const float*)d_in[5];
  const float* Wl = (const float*)d_in[6];
  const float* bl = (const float*)d_in[7];
  float* out = (float*)d_out;

  char* ws = (char*)d_ws;
  size_t off = 0;
  auto alloc = [&](size_t bytes) { void* p = ws + off; off += (bytes + 255) & ~(size_t)255; return p; };
  unsigned short* xb  = (unsigned short*)alloc((size_t)N_TOK * DMODEL * 2);
  unsigned short* W1b = (unsigned short*)alloc((size_t)NEXP * DMODEL * HDIM * 2);
  unsigned short* W2b = (unsigned short*)alloc((size_t)NEXP * DMODEL * HDIM * 2);
  unsigned short* Wlb = (unsigned short*)alloc((size_t)NCLS_PAD * DMODEL * 2);
  unsigned short* hws = (unsigned short*)alloc((size_t)NEXP * CAP * HDIM * 2);
  unsigned short* yb  = (unsigned short*)alloc((size_t)N_TOK * DMODEL * 2);
  int*   eidx = (int*)alloc(N_TOK * 4);
  float* gate = (float*)alloc(N_TOK * 4);
  int*   slot = (int*)alloc(NEXP * CAP * 4);
  float* psum = (float*)alloc(64);
  unsigned* cnt = (unsigned*)alloc(64);

  hipMemsetAsync(psum, 0, 64, stream);
  hipMemsetAsync(cnt, 0, 64, stream);
  hipMemsetAsync(slot, 0xFF, (size_t)NEXP * CAP * 4, stream);   // -1
  hipMemsetAsync(yb, 0, (size_t)N_TOK * DMODEL * 2, stream);

  // weight conversions (fp32 -> bf16, transposed to K-major rows)
  transpose_k<<<dim3(HDIM / 64, DMODEL / 64, NEXP), 256, 0, stream>>>(
      W1, W1b, DMODEL, HDIM, (long)DMODEL * HDIM, (long)DMODEL * HDIM);
  transpose_k<<<dim3(DMODEL / 64, HDIM / 64, NEXP), 256, 0, stream>>>(
      W2, W2b, HDIM, DMODEL, (long)DMODEL * HDIM, (long)DMODEL * HDIM);
  transpose_k<<<dim3(NCLS_PAD / 64, DMODEL / 64, 1), 256, 0, stream>>>(
      Wl, Wlb, DMODEL, NCLS, 0, 0);

  gating_k<<<256, 256, 0, stream>>>(x, Wg, xb, eidx, gate, psum, cnt);
  scan_k<<<1, 256, 0, stream>>>(eidx, slot, psum, cnt, out + (size_t)N_TOK * NCLS);

  gemm_k<0><<<dim3(HDIM / 128, CAP / 128, NEXP), 256, 0, stream>>>(
      xb, W1b, b1, hws, nullptr, slot, nullptr);
  gemm_k<1><<<dim3(DMODEL / 128, CAP / 128, NEXP), 256, 0, stream>>>(
      hws, W2b, b2, yb, nullptr, slot, gate);
  gemm_k<2><<<dim3(NCLS_PAD / 128, N_TOK / 128, 1), 256, 0, stream>>>(
      yb, Wlb, bl, nullptr, out, nullptr, nullptr);
}